// Round 3
// baseline (174.686 us; speedup 1.0000x reference)
//
#include <hip/hip_runtime.h>
#include <hip/hip_bf16.h>

#define DI __device__ __forceinline__

typedef __attribute__((ext_vector_type(8))) __bf16 bf16x8;
typedef __attribute__((ext_vector_type(4))) float f32x4;
typedef __attribute__((ext_vector_type(8))) short short8;
typedef __attribute__((ext_vector_type(4))) short short4v;
typedef unsigned short u16;

static constexpr int BB = 4, SS = 2048, EE = 1024, AA = 1024;

DI float bf2f(u16 u) { unsigned v = ((unsigned)u) << 16; float f; __builtin_memcpy(&f, &v, 4); return f; }
DI u16 f2bf(float f) { __hip_bfloat16 h = __float2bfloat16(f); u16 u; __builtin_memcpy(&u, &h, 2); return u; }

DI void gload16(const void* g, void* l) {
  __builtin_amdgcn_global_load_lds((const __attribute__((address_space(1))) void*)g,
                                   (__attribute__((address_space(3))) void*)l, 16, 0, 0);
}

// bijective XCD swizzle: nwg % 8 == 0. Each XCD gets a contiguous chunk.
DI int xcd_swz(int lin, int nwg) {
  int cpx = nwg >> 3;
  return (lin & 7) * cpx + (lin >> 3);
}

// LDS tile rows are 128B (64 bf16). Physical 16B chunk = logical ^ (row&7).
DI bf16x8 read_frag(const char* lds, int R, int c) {
  return *(const bf16x8*)(lds + R * 128 + ((c ^ (R & 7)) << 4));
}

// ================= 256x256 pipelined GEMM (proj): C[8192][3072] = Xb @ Wt^T =================
// 512 threads = 8 waves (2M x 4N). BK=64. LDS 128KB: 2 x (As 32KB + Bs 32KB).
// Counted vmcnt: prefetch 2 K-tiles ahead, wait vmcnt(8) (= next tile's loads still in flight).
static constexpr int PNK = EE / 64;  // 16 K-tiles

__global__ __launch_bounds__(512, 2) void k_proj2(const u16* __restrict__ Xb, const u16* __restrict__ Wt,
                                                  u16* __restrict__ Qb) {
  __shared__ __align__(16) char smem[131072];
  const int tid = threadIdx.x, lane = tid & 63, wid = tid >> 6;
  const int wr = wid >> 2, wc = wid & 3;
  const int lin = blockIdx.y * gridDim.x + blockIdx.x;  // 384 wgs
  const int wg = xcd_swz(lin, 384);
  const int mt = wg / 12, nt = wg % 12;
  const u16* Ap = Xb + (size_t)mt * 256 * EE;
  const u16* Bp = Wt + (size_t)nt * 256 * EE;

  f32x4 acc[8][4];
#pragma unroll
  for (int i = 0; i < 8; ++i)
#pragma unroll
    for (int j = 0; j < 4; ++j) acc[i][j] = (f32x4)0.f;

  auto STAGE = [&](int kt) {
    char* As = smem + (kt & 1) * 65536;
    char* Bs = As + 32768;
    const u16* a = Ap + kt * 64;
    const u16* b = Bp + kt * 64;
#pragma unroll
    for (int i = 0; i < 4; ++i) {
      int blk = i * 8 + wid;            // 1KB block 0..31 (8 rows each)
      int r = blk * 8 + (lane >> 3);    // tile row 0..255
      int c = (lane & 7) ^ (r & 7);     // logical k-chunk for this physical slot
      gload16((const char*)(a + (size_t)r * EE) + c * 16, As + blk * 1024);
      gload16((const char*)(b + (size_t)r * EE) + c * 16, Bs + blk * 1024);
    }
  };

  STAGE(0);
  STAGE(1);
  for (int kt = 0; kt < PNK; ++kt) {
    const char* As = smem + (kt & 1) * 65536;
    const char* Bs = As + 32768;
    if (kt + 1 < PNK) asm volatile("s_waitcnt vmcnt(8)" ::: "memory");
    else              asm volatile("s_waitcnt vmcnt(0)" ::: "memory");
    __builtin_amdgcn_sched_barrier(0);
    __builtin_amdgcn_s_barrier();     // all waves' kt data landed
    __builtin_amdgcn_sched_barrier(0);
    bf16x8 bfr[4][2];
#pragma unroll
    for (int ni = 0; ni < 4; ++ni)
#pragma unroll
      for (int ks = 0; ks < 2; ++ks)
        bfr[ni][ks] = read_frag(Bs, wc * 64 + ni * 16 + (lane & 15), ks * 4 + (lane >> 4));
#pragma unroll
    for (int q = 0; q < 4; ++q) {     // 4 phases: mi-pairs
      bf16x8 af[2][2];
#pragma unroll
      for (int m2 = 0; m2 < 2; ++m2)
#pragma unroll
        for (int ks = 0; ks < 2; ++ks)
          af[m2][ks] = read_frag(As, wr * 128 + (q * 2 + m2) * 16 + (lane & 15), ks * 4 + (lane >> 4));
      __builtin_amdgcn_s_setprio(1);
#pragma unroll
      for (int m2 = 0; m2 < 2; ++m2)
#pragma unroll
        for (int ni = 0; ni < 4; ++ni)
#pragma unroll
          for (int ks = 0; ks < 2; ++ks)
            acc[q * 2 + m2][ni] =
                __builtin_amdgcn_mfma_f32_16x16x32_bf16(af[m2][ks], bfr[ni][ks], acc[q * 2 + m2][ni], 0, 0, 0);
      __builtin_amdgcn_s_setprio(0);
    }
    __builtin_amdgcn_sched_barrier(0);
    __builtin_amdgcn_s_barrier();     // all waves done reading buf[kt&1]
    __builtin_amdgcn_sched_barrier(0);
    if (kt + 2 < PNK) STAGE(kt + 2);  // overwrite freed buffer; latency hides under kt+1 compute
  }

  // epilogue: C/D layout col=lane&15, row=(lane>>4)*4+reg
  const int lane15 = lane & 15, lhi = lane >> 4;
  const int w = nt >> 2;
  const int cb = (nt & 3) * 256 + wc * 64;
  const int r0 = mt * 256 + wr * 128;
  u16* Op = Qb + (size_t)w * ((size_t)BB * SS * AA);
#pragma unroll
  for (int mi = 0; mi < 8; ++mi)
#pragma unroll
    for (int ni = 0; ni < 4; ++ni)
#pragma unroll
      for (int r = 0; r < 4; ++r) {
        int row = r0 + mi * 16 + lhi * 4 + r;
        int col = cb + ni * 16 + lane15;
        Op[(size_t)row * AA + col] = f2bf(acc[mi][ni][r]);
      }
}

// ================= 128x128 GEMM core (scores / pv) =================
DI void stage_tile(const u16* g, int ld, char* lds, int wid, int lane) {
#pragma unroll
  for (int i = 0; i < 4; ++i) {
    int blk = i * 4 + wid;
    int r = blk * 8 + (lane >> 3);
    int c = (lane & 7) ^ (r & 7);
    gload16((const char*)(g + (size_t)r * ld) + c * 16, lds + blk * 1024);
  }
}

DI void gemm_tile(const u16* Ap, int lda, const u16* Bp, int ldb, int ksteps,
                  char* As, char* Bs, f32x4 acc[4][4]) {
  const int tid = threadIdx.x, lane = tid & 63, wid = tid >> 6;
  const int wr = wid >> 1, wc = wid & 1;
  for (int ks = 0; ks < ksteps; ++ks) {
    __syncthreads();
    stage_tile(Ap + (size_t)ks * 64, lda, As, wid, lane);
    stage_tile(Bp + (size_t)ks * 64, ldb, Bs, wid, lane);
    asm volatile("s_waitcnt vmcnt(0)" ::: "memory");
    __syncthreads();
#pragma unroll
    for (int ksub = 0; ksub < 2; ++ksub) {
      const int c = ksub * 4 + (lane >> 4);
      bf16x8 af[4], bfr[4];
#pragma unroll
      for (int mi = 0; mi < 4; ++mi) af[mi] = read_frag(As, wr * 64 + mi * 16 + (lane & 15), c);
#pragma unroll
      for (int ni = 0; ni < 4; ++ni) bfr[ni] = read_frag(Bs, wc * 64 + ni * 16 + (lane & 15), c);
#pragma unroll
      for (int mi = 0; mi < 4; ++mi)
#pragma unroll
        for (int ni = 0; ni < 4; ++ni)
          acc[mi][ni] = __builtin_amdgcn_mfma_f32_16x16x32_bf16(af[mi], bfr[ni], acc[mi][ni], 0, 0, 0);
    }
  }
}

// ---------- kernel 1: cast X fp32 -> bf16 ----------
__global__ __launch_bounds__(256) void k_castx(const float* __restrict__ X, u16* __restrict__ Xb) {
  size_t i = ((size_t)blockIdx.x * 256 + threadIdx.x) * 4;
  f32x4 f = *(const f32x4*)(X + i);
  short4v o;
#pragma unroll
  for (int j = 0; j < 4; ++j) o[j] = (short)f2bf(f[j]);
  *(short4v*)(Xb + i) = o;
}

// ---------- kernel 2: cast+transpose W -> Wt bf16 (Wt[n][k] = W[k][n]) ----------
__global__ __launch_bounds__(256) void k_wt(const float* __restrict__ Wq, const float* __restrict__ Wk,
                                            const float* __restrict__ Wv, u16* __restrict__ Wt) {
  __shared__ float t[64][65];
  const int k0 = blockIdx.x * 64, n0 = blockIdx.y * 64, w = blockIdx.z;
  const float* W = (w == 0) ? Wq : ((w == 1) ? Wk : Wv);
  u16* Wo = Wt + (size_t)w * EE * AA;
  const int tx = threadIdx.x & 63, ty = threadIdx.x >> 6;
#pragma unroll
  for (int r = 0; r < 16; ++r) {
    int k = r * 4 + ty;
    t[k][tx] = W[(size_t)(k0 + k) * AA + n0 + tx];
  }
  __syncthreads();
#pragma unroll
  for (int r = 0; r < 16; ++r) {
    int n = r * 4 + ty;
    Wo[(size_t)(n0 + n) * EE + k0 + tx] = f2bf(t[tx][n]);
  }
}

// ---------- kernel 4: transpose V -> Vt (Vt[a][s] = V[s][a]) ----------
__global__ __launch_bounds__(256) void k_vt(const u16* __restrict__ V, u16* __restrict__ Vt) {
  __shared__ u16 t[64][66];
  const int s0 = blockIdx.x * 64, a0 = blockIdx.y * 64, b = blockIdx.z;
  const u16* Vb = V + (size_t)b * SS * AA;
  u16* Vo = Vt + (size_t)b * AA * SS;
  const int tx = threadIdx.x & 63, ty = threadIdx.x >> 6;
#pragma unroll
  for (int r = 0; r < 16; ++r) {
    int s = r * 4 + ty;
    t[s][tx] = Vb[(size_t)(s0 + s) * AA + a0 + tx];
  }
  __syncthreads();
#pragma unroll
  for (int r = 0; r < 16; ++r) {
    int a = r * 4 + ty;
    Vo[(size_t)(a0 + a) * SS + s0 + tx] = t[tx][a];
  }
}

// ---------- kernel 5: P = exp(Q @ K^T / 32) causal, + rowsum atomics ----------
__global__ __launch_bounds__(256) void k_scores(const u16* __restrict__ Q, const u16* __restrict__ K,
                                                u16* __restrict__ Sc, float* __restrict__ rowsum) {
  __shared__ __align__(16) char smem[32768];
  const int wg = xcd_swz(blockIdx.x, 544);
  const int b = wg / 136, t = wg % 136;
  int i = (int)((sqrtf(8.f * t + 1.f) - 1.f) * 0.5f);
  while ((i + 1) * (i + 2) / 2 <= t) ++i;
  while (i * (i + 1) / 2 > t) --i;
  const int j = t - i * (i + 1) / 2;
  const u16* Ap = Q + (size_t)b * SS * AA + (size_t)i * 128 * AA;
  const u16* Bp = K + (size_t)b * SS * AA + (size_t)j * 128 * AA;
  u16* Op = Sc + (size_t)b * SS * SS;
  float* rs = rowsum + (size_t)b * SS;
  f32x4 acc[4][4];
#pragma unroll
  for (int x = 0; x < 4; ++x)
#pragma unroll
    for (int y = 0; y < 4; ++y) acc[x][y] = (f32x4)0.f;
  gemm_tile(Ap, AA, Bp, AA, AA / 64, smem, smem + 16384, acc);
  const int lane = threadIdx.x & 63, wid = threadIdx.x >> 6;
  const int r0 = i * 128 + (wid >> 1) * 64, c0 = j * 128 + (wid & 1) * 64;
#pragma unroll
  for (int mi = 0; mi < 4; ++mi)
#pragma unroll
    for (int r = 0; r < 4; ++r) {
      const int row = r0 + mi * 16 + ((lane >> 4) << 2) + r;
      float psum = 0.f;
#pragma unroll
      for (int ni = 0; ni < 4; ++ni) {
        const int col = c0 + ni * 16 + (lane & 15);
        float e = (col <= row) ? __expf(acc[mi][ni][r] * 0.03125f) : 0.f;
        psum += e;
        Op[(size_t)row * SS + col] = f2bf(e);
      }
      psum += __shfl_xor(psum, 1, 16);
      psum += __shfl_xor(psum, 2, 16);
      psum += __shfl_xor(psum, 4, 16);
      psum += __shfl_xor(psum, 8, 16);
      if ((lane & 15) == 0) atomicAdd(&rs[row], psum);
    }
}

// ---------- kernel 6: out = (P @ Vt^T) / rowsum (causal K-loop), fp32 out ----------
// XCD-balanced mapping: each XCD gets pairs {i, i+8} (equal flops); 8 nt blocks of a
// (b,i) pair stay on one XCD for P-panel L2 reuse.
__global__ __launch_bounds__(256) void k_pv(const u16* __restrict__ Sc, const u16* __restrict__ Vt,
                                            const float* __restrict__ rowsum, float* __restrict__ Out) {
  __shared__ __align__(16) char smem[32768];
  const int lin = blockIdx.y * gridDim.x + blockIdx.x;  // 512
  const int x = lin & 7, j = lin >> 3;
  const int pair = x + 8 * (j >> 3);   // (b,i) pair, pair%8 == xcd
  const int nt = j & 7;
  const int b = pair >> 4, i = pair & 15;
  const u16* Ap = Sc + (size_t)b * SS * SS + (size_t)i * 128 * SS;
  const u16* Bp = Vt + (size_t)b * AA * SS + (size_t)nt * 128 * SS;
  const float* rs = rowsum + (size_t)b * SS;
  float* Op = Out + (size_t)b * SS * AA;
  f32x4 acc[4][4];
#pragma unroll
  for (int p = 0; p < 4; ++p)
#pragma unroll
    for (int q = 0; q < 4; ++q) acc[p][q] = (f32x4)0.f;
  gemm_tile(Ap, SS, Bp, SS, 2 * (i + 1), smem, smem + 16384, acc);
  const int lane = threadIdx.x & 63, wid = threadIdx.x >> 6;
  const int r0 = i * 128 + (wid >> 1) * 64, c0 = nt * 128 + (wid & 1) * 64;
#pragma unroll
  for (int mi = 0; mi < 4; ++mi)
#pragma unroll
    for (int r = 0; r < 4; ++r) {
      const int row = r0 + mi * 16 + ((lane >> 4) << 2) + r;
      const float inv = 1.f / rs[row];
#pragma unroll
      for (int ni = 0; ni < 4; ++ni) {
        const int col = c0 + ni * 16 + (lane & 15);
        Op[(size_t)row * AA + col] = acc[mi][ni][r] * inv;
      }
    }
}

extern "C" void kernel_launch(void* const* d_in, const int* in_sizes, int n_in,
                              void* d_out, int out_size, void* d_ws, size_t ws_size,
                              hipStream_t stream) {
  const float* X  = (const float*)d_in[0];
  const float* Wq = (const float*)d_in[1];
  const float* Wk = (const float*)d_in[2];
  const float* Wv = (const float*)d_in[3];
  float* Out = (float*)d_out;
  char* ws = (char*)d_ws;
  u16* Xb = (u16*)ws;                              // 16 MiB: [8192][1024]
  u16* Wt = (u16*)(ws + (16u << 20));              // 6 MiB: [3072][1024] (n-major, Q|K|V)
  u16* Qb = (u16*)(ws + (22u << 20));              // 16 MiB  } contiguous:
  u16* Kb = (u16*)(ws + (38u << 20));              // 16 MiB  }  Qb + w*8192*1024
  u16* Vb = (u16*)(ws + (54u << 20));              // 16 MiB  }
  u16* Vt = (u16*)(ws + (70u << 20));              // 16 MiB: per-batch [1024][2048]
  u16* Sc = (u16*)(ws + (86u << 20));              // 32 MiB: [4][2048][2048]
  float* rowsum = (float*)(ws + (118u << 20));     // 32 KiB: [4][2048]

  k_castx<<<dim3((BB * SS * EE) / (256 * 4)), 256, 0, stream>>>(X, Xb);
  k_wt<<<dim3(16, 16, 3), 256, 0, stream>>>(Wq, Wk, Wv, Wt);
  k_proj2<<<dim3(12, 32), 512, 0, stream>>>(Xb, Wt, Qb);
  k_vt<<<dim3(SS / 64, AA / 64, BB), 256, 0, stream>>>(Vb, Vt);
  hipMemsetAsync(rowsum, 0, BB * SS * sizeof(float), stream);
  k_scores<<<dim3(136 * BB), 256, 0, stream>>>(Qb, Kb, Sc, rowsum);
  k_pv<<<dim3(8, 64), 256, 0, stream>>>(Sc, Vt, rowsum, Out);
}

// Round 4
// 173.812 us; speedup vs baseline: 1.0050x; 1.0050x over previous
//
#include <hip/hip_runtime.h>
#include <hip/hip_bf16.h>

#define DI __device__ __forceinline__

typedef __attribute__((ext_vector_type(8))) __bf16 bf16x8;
typedef __attribute__((ext_vector_type(4))) float f32x4;
typedef __attribute__((ext_vector_type(8))) short short8;
typedef __attribute__((ext_vector_type(4))) short short4v;
typedef unsigned short u16;

static constexpr int BB = 4, SS = 2048, EE = 1024, AA = 1024;

DI float bf2f(u16 u) { unsigned v = ((unsigned)u) << 16; float f; __builtin_memcpy(&f, &v, 4); return f; }
DI u16 f2bf(float f) { __hip_bfloat16 h = __float2bfloat16(f); u16 u; __builtin_memcpy(&u, &h, 2); return u; }

DI void gload16(const void* g, void* l) {
  __builtin_amdgcn_global_load_lds((const __attribute__((address_space(1))) void*)g,
                                   (__attribute__((address_space(3))) void*)l, 16, 0, 0);
}

// bijective XCD swizzle: nwg % 8 == 0.
DI int xcd_swz(int lin, int nwg) {
  int cpx = nwg >> 3;
  return (lin & 7) * cpx + (lin >> 3);
}

// LDS tile rows are 128B (64 bf16). Physical 16B chunk = logical ^ (row&7).
DI bf16x8 read_frag(const char* lds, int R, int c) {
  return *(const bf16x8*)(lds + R * 128 + ((c ^ (R & 7)) << 4));
}

// ================= proj: 256x128-tile pipelined GEMM, C[8192][3072] = Xb @ Wt^T =================
// 512 threads = 8 waves (4M x 2N), per-wave 64x64. BK=64, 16 K-tiles.
// Triple-buffered LDS (3 x 48KB): compute buf t%3, stage t+2 into (t+2)%3 (freed at t-1's end).
// Per K-tile: 2 phases (ks=0 / ks=1), each {8 ds_read || 3 gload_lds, barrier, lgkm0, 16 MFMA, barrier}.
// Counted vmcnt(6) once per K-tile (phase B) = leave tile t+2's 6 loads in flight.
static constexpr int PNK = 16;
static constexpr int PTB = 49152;  // per-buffer bytes: A 32KB + B 16KB

__global__ __launch_bounds__(512, 2) void k_proj3(const u16* __restrict__ Xb, const u16* __restrict__ Wt,
                                                  u16* __restrict__ Qb) {
  __shared__ __align__(16) char smem[3 * PTB];  // 144 KB
  const int tid = threadIdx.x, lane = tid & 63, wid = tid >> 6;
  const int wr = wid >> 1, wc = wid & 1;        // 4M x 2N waves
  const int lin = blockIdx.x;                   // 768 wgs; lin&7 = XCD (round-robin dispatch)
  const int jj = lin >> 3;                      // [0,96) within XCD
  const int mt = (lin & 7) * 4 + (jj & 3);      // [0,32): 4 m-tiles per XCD
  const int nt = jj >> 2;                       // [0,24): m-fastest order
  const u16* Ap = Xb + (size_t)mt * 256 * EE;
  const u16* Bp = Wt + (size_t)nt * 128 * EE;

  // A-half: rows half*128..+128 -> blocks half*16..+16 (2 loads/thread)
  auto stageA = [&](int t, int buf, int half) {
#pragma unroll
    for (int i = 0; i < 2; ++i) {
      int blk = half * 16 + i * 8 + wid;        // 1KB block within A region (32 blocks)
      int r = blk * 8 + (lane >> 3);            // tile row 0..255
      int c = (lane & 7) ^ (r & 7);
      gload16((const char*)(Ap + (size_t)t * 64 + (size_t)r * EE) + c * 16,
              smem + buf * PTB + blk * 1024);
    }
  };
  // B-half: rows half*64..+64 -> blocks half*8..+8 (1 load/thread)
  auto stageB = [&](int t, int buf, int half) {
    int blk = half * 8 + wid;                   // within B region (16 blocks)
    int r = blk * 8 + (lane >> 3);              // row 0..127
    int c = (lane & 7) ^ (r & 7);
    gload16((const char*)(Bp + (size_t)t * 64 + (size_t)r * EE) + c * 16,
            smem + buf * PTB + 32768 + blk * 1024);
  };

  f32x4 acc[4][4];
#pragma unroll
  for (int i = 0; i < 4; ++i)
#pragma unroll
    for (int j = 0; j < 4; ++j) acc[i][j] = (f32x4)0.f;

  // prologue: tile0 -> buf0 (6 loads), tile1 -> buf1 (6 loads)
  stageA(0, 0, 0); stageA(0, 0, 1); stageB(0, 0, 0); stageB(0, 0, 1);
  stageA(1, 1, 0); stageA(1, 1, 1); stageB(1, 1, 0); stageB(1, 1, 1);
  asm volatile("s_waitcnt vmcnt(6)" ::: "memory");  // tile0 landed
  __builtin_amdgcn_s_barrier();

  int cb = 0;
#pragma unroll 1
  for (int t = 0; t < PNK; ++t) {
    const char* As = smem + cb * PTB;
    const char* Bs = As + 32768;
    const int sb = (cb >= 1) ? cb - 1 : 2;      // (cb+2)%3
    const bool st = (t + 2 < PNK);

    // ---------- phase A: ks = 0 ----------
    {
      const int ch = (lane >> 4);               // chunk = ks*4 + (lane>>4)
      bf16x8 a0[4], b0[4];
#pragma unroll
      for (int mi = 0; mi < 4; ++mi) a0[mi] = read_frag(As, wr * 64 + mi * 16 + (lane & 15), ch);
#pragma unroll
      for (int ni = 0; ni < 4; ++ni) b0[ni] = read_frag(Bs, wc * 64 + ni * 16 + (lane & 15), ch);
      if (st) { stageA(t + 2, sb, 0); stageB(t + 2, sb, 0); }
      __builtin_amdgcn_s_barrier();
      asm volatile("s_waitcnt lgkmcnt(0)" ::: "memory");
      __builtin_amdgcn_sched_barrier(0);
      __builtin_amdgcn_s_setprio(1);
#pragma unroll
      for (int mi = 0; mi < 4; ++mi)
#pragma unroll
        for (int ni = 0; ni < 4; ++ni)
          acc[mi][ni] = __builtin_amdgcn_mfma_f32_16x16x32_bf16(a0[mi], b0[ni], acc[mi][ni], 0, 0, 0);
      __builtin_amdgcn_s_setprio(0);
      __builtin_amdgcn_sched_barrier(0);
      __builtin_amdgcn_s_barrier();
    }
    // ---------- phase B: ks = 1 ----------
    {
      const int ch = 4 + (lane >> 4);
      bf16x8 a1[4], b1[4];
#pragma unroll
      for (int mi = 0; mi < 4; ++mi) a1[mi] = read_frag(As, wr * 64 + mi * 16 + (lane & 15), ch);
#pragma unroll
      for (int ni = 0; ni < 4; ++ni) b1[ni] = read_frag(Bs, wc * 64 + ni * 16 + (lane & 15), ch);
      if (st) { stageA(t + 2, sb, 1); stageB(t + 2, sb, 1); }
      // drain tile t+1's 6 loads (leave t+2's 6 in flight); never 0 mid-loop
      if (t < PNK - 2)       asm volatile("s_waitcnt vmcnt(6)" ::: "memory");
      else if (t == PNK - 2) asm volatile("s_waitcnt vmcnt(0)" ::: "memory");
      __builtin_amdgcn_s_barrier();
      asm volatile("s_waitcnt lgkmcnt(0)" ::: "memory");
      __builtin_amdgcn_sched_barrier(0);
      __builtin_amdgcn_s_setprio(1);
#pragma unroll
      for (int mi = 0; mi < 4; ++mi)
#pragma unroll
        for (int ni = 0; ni < 4; ++ni)
          acc[mi][ni] = __builtin_amdgcn_mfma_f32_16x16x32_bf16(a1[mi], b1[ni], acc[mi][ni], 0, 0, 0);
      __builtin_amdgcn_s_setprio(0);
      __builtin_amdgcn_sched_barrier(0);
      __builtin_amdgcn_s_barrier();
    }
    cb = (cb >= 2) ? 0 : cb + 1;
  }

  // epilogue: C/D layout col=lane&15, row=(lane>>4)*4+reg
  const int w = nt >> 3;
  u16* Op = Qb + (size_t)w * ((size_t)BB * SS * AA);
  const int r0 = mt * 256 + wr * 64;
  const int c0 = (nt & 7) * 128 + wc * 64;
#pragma unroll
  for (int mi = 0; mi < 4; ++mi)
#pragma unroll
    for (int ni = 0; ni < 4; ++ni)
#pragma unroll
      for (int r = 0; r < 4; ++r) {
        int row = r0 + mi * 16 + ((lane >> 4) << 2) + r;
        int col = c0 + ni * 16 + (lane & 15);
        Op[(size_t)row * AA + col] = f2bf(acc[mi][ni][r]);
      }
}

// ================= 128x128 GEMM core (scores / pv) =================
DI void stage_tile(const u16* g, int ld, char* lds, int wid, int lane) {
#pragma unroll
  for (int i = 0; i < 4; ++i) {
    int blk = i * 4 + wid;
    int r = blk * 8 + (lane >> 3);
    int c = (lane & 7) ^ (r & 7);
    gload16((const char*)(g + (size_t)r * ld) + c * 16, lds + blk * 1024);
  }
}

DI void gemm_tile(const u16* Ap, int lda, const u16* Bp, int ldb, int ksteps,
                  char* As, char* Bs, f32x4 acc[4][4]) {
  const int tid = threadIdx.x, lane = tid & 63, wid = tid >> 6;
  const int wr = wid >> 1, wc = wid & 1;
  for (int ks = 0; ks < ksteps; ++ks) {
    __syncthreads();
    stage_tile(Ap + (size_t)ks * 64, lda, As, wid, lane);
    stage_tile(Bp + (size_t)ks * 64, ldb, Bs, wid, lane);
    asm volatile("s_waitcnt vmcnt(0)" ::: "memory");
    __syncthreads();
#pragma unroll
    for (int ksub = 0; ksub < 2; ++ksub) {
      const int c = ksub * 4 + (lane >> 4);
      bf16x8 af[4], bfr[4];
#pragma unroll
      for (int mi = 0; mi < 4; ++mi) af[mi] = read_frag(As, wr * 64 + mi * 16 + (lane & 15), c);
#pragma unroll
      for (int ni = 0; ni < 4; ++ni) bfr[ni] = read_frag(Bs, wc * 64 + ni * 16 + (lane & 15), c);
#pragma unroll
      for (int mi = 0; mi < 4; ++mi)
#pragma unroll
        for (int ni = 0; ni < 4; ++ni)
          acc[mi][ni] = __builtin_amdgcn_mfma_f32_16x16x32_bf16(af[mi], bfr[ni], acc[mi][ni], 0, 0, 0);
    }
  }
}

// ---------- cast X fp32 -> bf16 ----------
__global__ __launch_bounds__(256) void k_castx(const float* __restrict__ X, u16* __restrict__ Xb) {
  size_t i = ((size_t)blockIdx.x * 256 + threadIdx.x) * 4;
  f32x4 f = *(const f32x4*)(X + i);
  short4v o;
#pragma unroll
  for (int j = 0; j < 4; ++j) o[j] = (short)f2bf(f[j]);
  *(short4v*)(Xb + i) = o;
}

// ---------- cast+transpose W -> Wt bf16 (Wt[n][k] = W[k][n]) ----------
__global__ __launch_bounds__(256) void k_wt(const float* __restrict__ Wq, const float* __restrict__ Wk,
                                            const float* __restrict__ Wv, u16* __restrict__ Wt) {
  __shared__ float t[64][65];
  const int k0 = blockIdx.x * 64, n0 = blockIdx.y * 64, w = blockIdx.z;
  const float* W = (w == 0) ? Wq : ((w == 1) ? Wk : Wv);
  u16* Wo = Wt + (size_t)w * EE * AA;
  const int tx = threadIdx.x & 63, ty = threadIdx.x >> 6;
#pragma unroll
  for (int r = 0; r < 16; ++r) {
    int k = r * 4 + ty;
    t[k][tx] = W[(size_t)(k0 + k) * AA + n0 + tx];
  }
  __syncthreads();
#pragma unroll
  for (int r = 0; r < 16; ++r) {
    int n = r * 4 + ty;
    Wo[(size_t)(n0 + n) * EE + k0 + tx] = f2bf(t[tx][n]);
  }
}

// ---------- transpose V -> Vt (Vt[a][s] = V[s][a]) ----------
__global__ __launch_bounds__(256) void k_vt(const u16* __restrict__ V, u16* __restrict__ Vt) {
  __shared__ u16 t[64][66];
  const int s0 = blockIdx.x * 64, a0 = blockIdx.y * 64, b = blockIdx.z;
  const u16* Vb = V + (size_t)b * SS * AA;
  u16* Vo = Vt + (size_t)b * AA * SS;
  const int tx = threadIdx.x & 63, ty = threadIdx.x >> 6;
#pragma unroll
  for (int r = 0; r < 16; ++r) {
    int s = r * 4 + ty;
    t[s][tx] = Vb[(size_t)(s0 + s) * AA + a0 + tx];
  }
  __syncthreads();
#pragma unroll
  for (int r = 0; r < 16; ++r) {
    int a = r * 4 + ty;
    Vo[(size_t)(a0 + a) * SS + s0 + tx] = t[tx][a];
  }
}

// ---------- P = exp(Q @ K^T / 32) causal, + rowsum atomics ----------
__global__ __launch_bounds__(256) void k_scores(const u16* __restrict__ Q, const u16* __restrict__ K,
                                                u16* __restrict__ Sc, float* __restrict__ rowsum) {
  __shared__ __align__(16) char smem[32768];
  const int wg = xcd_swz(blockIdx.x, 544);
  const int b = wg / 136, t = wg % 136;
  int i = (int)((sqrtf(8.f * t + 1.f) - 1.f) * 0.5f);
  while ((i + 1) * (i + 2) / 2 <= t) ++i;
  while (i * (i + 1) / 2 > t) --i;
  const int j = t - i * (i + 1) / 2;
  const u16* Ap = Q + (size_t)b * SS * AA + (size_t)i * 128 * AA;
  const u16* Bp = K + (size_t)b * SS * AA + (size_t)j * 128 * AA;
  u16* Op = Sc + (size_t)b * SS * SS;
  float* rs = rowsum + (size_t)b * SS;
  f32x4 acc[4][4];
#pragma unroll
  for (int x = 0; x < 4; ++x)
#pragma unroll
    for (int y = 0; y < 4; ++y) acc[x][y] = (f32x4)0.f;
  gemm_tile(Ap, AA, Bp, AA, AA / 64, smem, smem + 16384, acc);
  const int lane = threadIdx.x & 63, wid = threadIdx.x >> 6;
  const int r0 = i * 128 + (wid >> 1) * 64, c0 = j * 128 + (wid & 1) * 64;
#pragma unroll
  for (int mi = 0; mi < 4; ++mi)
#pragma unroll
    for (int r = 0; r < 4; ++r) {
      const int row = r0 + mi * 16 + ((lane >> 4) << 2) + r;
      float psum = 0.f;
#pragma unroll
      for (int ni = 0; ni < 4; ++ni) {
        const int col = c0 + ni * 16 + (lane & 15);
        float e = (col <= row) ? __expf(acc[mi][ni][r] * 0.03125f) : 0.f;
        psum += e;
        Op[(size_t)row * SS + col] = f2bf(e);
      }
      psum += __shfl_xor(psum, 1, 16);
      psum += __shfl_xor(psum, 2, 16);
      psum += __shfl_xor(psum, 4, 16);
      psum += __shfl_xor(psum, 8, 16);
      if ((lane & 15) == 0) atomicAdd(&rs[row], psum);
    }
}

// ---------- out = (P @ Vt^T) / rowsum (causal K-loop), fp32 out ----------
__global__ __launch_bounds__(256) void k_pv(const u16* __restrict__ Sc, const u16* __restrict__ Vt,
                                            const float* __restrict__ rowsum, float* __restrict__ Out) {
  __shared__ __align__(16) char smem[32768];
  const int lin = blockIdx.y * gridDim.x + blockIdx.x;  // 512
  const int x = lin & 7, j = lin >> 3;
  const int pair = x + 8 * (j >> 3);   // (b,i) pair; balanced {i, i+8} per XCD
  const int nt = j & 7;
  const int b = pair >> 4, i = pair & 15;
  const u16* Ap = Sc + (size_t)b * SS * SS + (size_t)i * 128 * SS;
  const u16* Bp = Vt + (size_t)b * AA * SS + (size_t)nt * 128 * SS;
  const float* rs = rowsum + (size_t)b * SS;
  float* Op = Out + (size_t)b * SS * AA;
  f32x4 acc[4][4];
#pragma unroll
  for (int p = 0; p < 4; ++p)
#pragma unroll
    for (int q = 0; q < 4; ++q) acc[p][q] = (f32x4)0.f;
  gemm_tile(Ap, SS, Bp, SS, 2 * (i + 1), smem, smem + 16384, acc);
  const int lane = threadIdx.x & 63, wid = threadIdx.x >> 6;
  const int r0 = i * 128 + (wid >> 1) * 64, c0 = nt * 128 + (wid & 1) * 64;
#pragma unroll
  for (int mi = 0; mi < 4; ++mi)
#pragma unroll
    for (int r = 0; r < 4; ++r) {
      const int row = r0 + mi * 16 + ((lane >> 4) << 2) + r;
      const float inv = 1.f / rs[row];
#pragma unroll
      for (int ni = 0; ni < 4; ++ni) {
        const int col = c0 + ni * 16 + (lane & 15);
        Op[(size_t)row * AA + col] = acc[mi][ni][r] * inv;
      }
    }
}

extern "C" void kernel_launch(void* const* d_in, const int* in_sizes, int n_in,
                              void* d_out, int out_size, void* d_ws, size_t ws_size,
                              hipStream_t stream) {
  const float* X  = (const float*)d_in[0];
  const float* Wq = (const float*)d_in[1];
  const float* Wk = (const float*)d_in[2];
  const float* Wv = (const float*)d_in[3];
  float* Out = (float*)d_out;
  char* ws = (char*)d_ws;
  u16* Xb = (u16*)ws;                              // 16 MiB: [8192][1024]
  u16* Wt = (u16*)(ws + (16u << 20));              // 6 MiB: [3072][1024] (n-major, Q|K|V)
  u16* Qb = (u16*)(ws + (22u << 20));              // 16 MiB  } contiguous:
  u16* Kb = (u16*)(ws + (38u << 20));              // 16 MiB  }  Qb + w*8192*1024
  u16* Vb = (u16*)(ws + (54u << 20));              // 16 MiB  }
  u16* Vt = (u16*)(ws + (70u << 20));              // 16 MiB: per-batch [1024][2048]
  u16* Sc = (u16*)(ws + (86u << 20));              // 32 MiB: [4][2048][2048]
  float* rowsum = (float*)(ws + (118u << 20));     // 32 KiB: [4][2048]

  k_castx<<<dim3((BB * SS * EE) / (256 * 4)), 256, 0, stream>>>(X, Xb);
  k_wt<<<dim3(16, 16, 3), 256, 0, stream>>>(Wq, Wk, Wv, Wt);
  k_proj3<<<dim3(768), 512, 0, stream>>>(Xb, Wt, Qb);
  k_vt<<<dim3(SS / 64, AA / 64, BB), 256, 0, stream>>>(Vb, Vt);
  hipMemsetAsync(rowsum, 0, BB * SS * sizeof(float), stream);
  k_scores<<<dim3(136 * BB), 256, 0, stream>>>(Qb, Kb, Sc, rowsum);
  k_pv<<<dim3(8, 64), 256, 0, stream>>>(Sc, Vt, rowsum, Out);
}

// Round 5
// 171.765 us; speedup vs baseline: 1.0170x; 1.0119x over previous
//
#include <hip/hip_runtime.h>
#include <hip/hip_bf16.h>

#define DI __device__ __forceinline__

typedef __attribute__((ext_vector_type(8))) __bf16 bf16x8;
typedef __attribute__((ext_vector_type(4))) float f32x4;
typedef __attribute__((ext_vector_type(8))) short short8;
typedef __attribute__((ext_vector_type(4))) short short4v;
typedef unsigned short u16;

static constexpr int BB = 4, SS = 2048, EE = 1024, AA = 1024;

DI float bf2f(u16 u) { unsigned v = ((unsigned)u) << 16; float f; __builtin_memcpy(&f, &v, 4); return f; }
DI u16 f2bf(float f) { __hip_bfloat16 h = __float2bfloat16(f); u16 u; __builtin_memcpy(&u, &h, 2); return u; }

DI void gload16(const void* g, void* l) {
  __builtin_amdgcn_global_load_lds((const __attribute__((address_space(1))) void*)g,
                                   (__attribute__((address_space(3))) void*)l, 16, 0, 0);
}

// bijective XCD swizzle: nwg % 8 == 0.
DI int xcd_swz(int lin, int nwg) {
  int cpx = nwg >> 3;
  return (lin & 7) * cpx + (lin >> 3);
}

// LDS tile rows are 128B (64 bf16). Physical 16B chunk = logical ^ (row&7).
DI bf16x8 read_frag(const char* lds, int R, int c) {
  return *(const bf16x8*)(lds + R * 128 + ((c ^ (R & 7)) << 4));
}

// ================= proj: 256x128-tile pipelined GEMM, C[8192][3072] = Xb @ Wt^T =================
// 512 threads = 8 waves (4M x 2N), per-wave 64x64. BK=64, 16 K-tiles.
// Triple-buffered LDS (3 x 48KB): compute buf t%3, stage t+2 into (t+2)%3 (freed at t-1's end).
// Per K-tile: 2 phases (ks=0 / ks=1), each {8 ds_read || 3 gload_lds, barrier, lgkm0, 16 MFMA, barrier}.
// Counted vmcnt(6) once per K-tile (phase B) = leave tile t+2's 6 loads in flight.
static constexpr int PNK = 16;
static constexpr int PTB = 49152;  // per-buffer bytes: A 32KB + B 16KB

__global__ __launch_bounds__(512, 2) void k_proj3(const u16* __restrict__ Xb, const u16* __restrict__ Wt,
                                                  u16* __restrict__ Qb) {
  __shared__ __align__(16) char smem[3 * PTB];  // 144 KB
  const int tid = threadIdx.x, lane = tid & 63, wid = tid >> 6;
  const int wr = wid >> 1, wc = wid & 1;        // 4M x 2N waves
  const int lin = blockIdx.x;                   // 768 wgs; lin&7 = XCD (round-robin dispatch)
  const int jj = lin >> 3;                      // [0,96) within XCD
  const int mt = (lin & 7) * 4 + (jj & 3);      // [0,32): 4 m-tiles per XCD
  const int nt = jj >> 2;                       // [0,24): m-fastest order
  const u16* Ap = Xb + (size_t)mt * 256 * EE;
  const u16* Bp = Wt + (size_t)nt * 128 * EE;

  auto stageA = [&](int t, int buf, int half) {
#pragma unroll
    for (int i = 0; i < 2; ++i) {
      int blk = half * 16 + i * 8 + wid;
      int r = blk * 8 + (lane >> 3);
      int c = (lane & 7) ^ (r & 7);
      gload16((const char*)(Ap + (size_t)t * 64 + (size_t)r * EE) + c * 16,
              smem + buf * PTB + blk * 1024);
    }
  };
  auto stageB = [&](int t, int buf, int half) {
    int blk = half * 8 + wid;
    int r = blk * 8 + (lane >> 3);
    int c = (lane & 7) ^ (r & 7);
    gload16((const char*)(Bp + (size_t)t * 64 + (size_t)r * EE) + c * 16,
            smem + buf * PTB + 32768 + blk * 1024);
  };

  f32x4 acc[4][4];
#pragma unroll
  for (int i = 0; i < 4; ++i)
#pragma unroll
    for (int j = 0; j < 4; ++j) acc[i][j] = (f32x4)0.f;

  stageA(0, 0, 0); stageA(0, 0, 1); stageB(0, 0, 0); stageB(0, 0, 1);
  stageA(1, 1, 0); stageA(1, 1, 1); stageB(1, 1, 0); stageB(1, 1, 1);
  asm volatile("s_waitcnt vmcnt(6)" ::: "memory");
  __builtin_amdgcn_s_barrier();

  int cb = 0;
#pragma unroll 1
  for (int t = 0; t < PNK; ++t) {
    const char* As = smem + cb * PTB;
    const char* Bs = As + 32768;
    const int sb = (cb >= 1) ? cb - 1 : 2;      // (cb+2)%3
    const bool st = (t + 2 < PNK);

    // ---------- phase A: ks = 0 ----------
    {
      const int ch = (lane >> 4);
      bf16x8 a0[4], b0[4];
#pragma unroll
      for (int mi = 0; mi < 4; ++mi) a0[mi] = read_frag(As, wr * 64 + mi * 16 + (lane & 15), ch);
#pragma unroll
      for (int ni = 0; ni < 4; ++ni) b0[ni] = read_frag(Bs, wc * 64 + ni * 16 + (lane & 15), ch);
      if (st) { stageA(t + 2, sb, 0); stageB(t + 2, sb, 0); }
      __builtin_amdgcn_s_barrier();
      asm volatile("s_waitcnt lgkmcnt(0)" ::: "memory");
      __builtin_amdgcn_sched_barrier(0);
      __builtin_amdgcn_s_setprio(1);
#pragma unroll
      for (int mi = 0; mi < 4; ++mi)
#pragma unroll
        for (int ni = 0; ni < 4; ++ni)
          acc[mi][ni] = __builtin_amdgcn_mfma_f32_16x16x32_bf16(a0[mi], b0[ni], acc[mi][ni], 0, 0, 0);
      __builtin_amdgcn_s_setprio(0);
      __builtin_amdgcn_sched_barrier(0);
      __builtin_amdgcn_s_barrier();
    }
    // ---------- phase B: ks = 1 ----------
    {
      const int ch = 4 + (lane >> 4);
      bf16x8 a1[4], b1[4];
#pragma unroll
      for (int mi = 0; mi < 4; ++mi) a1[mi] = read_frag(As, wr * 64 + mi * 16 + (lane & 15), ch);
#pragma unroll
      for (int ni = 0; ni < 4; ++ni) b1[ni] = read_frag(Bs, wc * 64 + ni * 16 + (lane & 15), ch);
      if (st) { stageA(t + 2, sb, 1); stageB(t + 2, sb, 1); }
      if (t < PNK - 2)       asm volatile("s_waitcnt vmcnt(6)" ::: "memory");
      else if (t == PNK - 2) asm volatile("s_waitcnt vmcnt(0)" ::: "memory");
      __builtin_amdgcn_s_barrier();
      asm volatile("s_waitcnt lgkmcnt(0)" ::: "memory");
      __builtin_amdgcn_sched_barrier(0);
      __builtin_amdgcn_s_setprio(1);
#pragma unroll
      for (int mi = 0; mi < 4; ++mi)
#pragma unroll
        for (int ni = 0; ni < 4; ++ni)
          acc[mi][ni] = __builtin_amdgcn_mfma_f32_16x16x32_bf16(a1[mi], b1[ni], acc[mi][ni], 0, 0, 0);
      __builtin_amdgcn_s_setprio(0);
      __builtin_amdgcn_sched_barrier(0);
      __builtin_amdgcn_s_barrier();
    }
    cb = (cb >= 2) ? 0 : cb + 1;
  }

  const int w = nt >> 3;
  u16* Op = Qb + (size_t)w * ((size_t)BB * SS * AA);
  const int r0 = mt * 256 + wr * 64;
  const int c0 = (nt & 7) * 128 + wc * 64;
#pragma unroll
  for (int mi = 0; mi < 4; ++mi)
#pragma unroll
    for (int ni = 0; ni < 4; ++ni)
#pragma unroll
      for (int r = 0; r < 4; ++r) {
        int row = r0 + mi * 16 + ((lane >> 4) << 2) + r;
        int col = c0 + ni * 16 + (lane & 15);
        Op[(size_t)row * AA + col] = f2bf(acc[mi][ni][r]);
      }
}

// ================= 128x128 GEMM core (scores / pv) =================
DI void stage_tile(const u16* g, int ld, char* lds, int wid, int lane) {
#pragma unroll
  for (int i = 0; i < 4; ++i) {
    int blk = i * 4 + wid;
    int r = blk * 8 + (lane >> 3);
    int c = (lane & 7) ^ (r & 7);
    gload16((const char*)(g + (size_t)r * ld) + c * 16, lds + blk * 1024);
  }
}

DI void gemm_tile(const u16* Ap, int lda, const u16* Bp, int ldb, int ksteps,
                  char* As, char* Bs, f32x4 acc[4][4]) {
  const int tid = threadIdx.x, lane = tid & 63, wid = tid >> 6;
  const int wr = wid >> 1, wc = wid & 1;
  for (int ks = 0; ks < ksteps; ++ks) {
    __syncthreads();
    stage_tile(Ap + (size_t)ks * 64, lda, As, wid, lane);
    stage_tile(Bp + (size_t)ks * 64, ldb, Bs, wid, lane);
    asm volatile("s_waitcnt vmcnt(0)" ::: "memory");
    __syncthreads();
#pragma unroll
    for (int ksub = 0; ksub < 2; ++ksub) {
      const int c = ksub * 4 + (lane >> 4);
      bf16x8 af[4], bfr[4];
#pragma unroll
      for (int mi = 0; mi < 4; ++mi) af[mi] = read_frag(As, wr * 64 + mi * 16 + (lane & 15), c);
#pragma unroll
      for (int ni = 0; ni < 4; ++ni) bfr[ni] = read_frag(Bs, wc * 64 + ni * 16 + (lane & 15), c);
#pragma unroll
      for (int mi = 0; mi < 4; ++mi)
#pragma unroll
        for (int ni = 0; ni < 4; ++ni)
          acc[mi][ni] = __builtin_amdgcn_mfma_f32_16x16x32_bf16(af[mi], bfr[ni], acc[mi][ni], 0, 0, 0);
    }
  }
}

// ---------- prep: cast X -> bf16, cast+transpose W -> Wt, zero rowsum ----------
// blocks [0,8192): castx (first 32 also zero rowsum); [8192, 8960): W transpose.
__global__ __launch_bounds__(256) void k_prep(const float* __restrict__ X, const float* __restrict__ Wq,
                                              const float* __restrict__ Wk, const float* __restrict__ Wv,
                                              u16* __restrict__ Xb, u16* __restrict__ Wt,
                                              float* __restrict__ rowsum) {
  __shared__ float t[64][65];
  const int bid = blockIdx.x;
  if (bid < 8192) {
    if (bid < 32) rowsum[bid * 256 + threadIdx.x] = 0.f;
    size_t i = ((size_t)bid * 256 + threadIdx.x) * 4;
    f32x4 f = *(const f32x4*)(X + i);
    short4v o;
#pragma unroll
    for (int j = 0; j < 4; ++j) o[j] = (short)f2bf(f[j]);
    *(short4v*)(Xb + i) = o;
  } else {
    const int bx = bid - 8192;                 // [0,768)
    const int w = bx >> 8, rem = bx & 255;
    const int k0 = (rem & 15) * 64, n0 = (rem >> 4) * 64;
    const float* W = (w == 0) ? Wq : ((w == 1) ? Wk : Wv);
    u16* Wo = Wt + (size_t)w * EE * AA;
    const int tx = threadIdx.x & 63, ty = threadIdx.x >> 6;
#pragma unroll
    for (int r = 0; r < 16; ++r) {
      int k = r * 4 + ty;
      t[k][tx] = W[(size_t)(k0 + k) * AA + n0 + tx];
    }
    __syncthreads();
#pragma unroll
    for (int r = 0; r < 16; ++r) {
      int n = r * 4 + ty;
      Wo[(size_t)(n0 + n) * EE + k0 + tx] = f2bf(t[tx][n]);
    }
  }
}

// ---------- transpose V -> Vt (Vt[a][s] = V[s][a]) ----------
__global__ __launch_bounds__(256) void k_vt(const u16* __restrict__ V, u16* __restrict__ Vt) {
  __shared__ u16 t[64][66];
  const int s0 = blockIdx.x * 64, a0 = blockIdx.y * 64, b = blockIdx.z;
  const u16* Vb = V + (size_t)b * SS * AA;
  u16* Vo = Vt + (size_t)b * AA * SS;
  const int tx = threadIdx.x & 63, ty = threadIdx.x >> 6;
#pragma unroll
  for (int r = 0; r < 16; ++r) {
    int s = r * 4 + ty;
    t[s][tx] = Vb[(size_t)(s0 + s) * AA + a0 + tx];
  }
  __syncthreads();
#pragma unroll
  for (int r = 0; r < 16; ++r) {
    int a = r * 4 + ty;
    Vo[(size_t)(a0 + a) * SS + s0 + tx] = t[tx][a];
  }
}

// ---------- P = exp(Q @ K^T / 32) causal, + rowsum atomics ----------
__global__ __launch_bounds__(256) void k_scores(const u16* __restrict__ Q, const u16* __restrict__ K,
                                                u16* __restrict__ Sc, float* __restrict__ rowsum) {
  __shared__ __align__(16) char smem[32768];
  const int wg = xcd_swz(blockIdx.x, 544);
  const int b = wg / 136, t = wg % 136;
  int i = (int)((sqrtf(8.f * t + 1.f) - 1.f) * 0.5f);
  while ((i + 1) * (i + 2) / 2 <= t) ++i;
  while (i * (i + 1) / 2 > t) --i;
  const int j = t - i * (i + 1) / 2;
  const u16* Ap = Q + (size_t)b * SS * AA + (size_t)i * 128 * AA;
  const u16* Bp = K + (size_t)b * SS * AA + (size_t)j * 128 * AA;
  u16* Op = Sc + (size_t)b * SS * SS;
  float* rs = rowsum + (size_t)b * SS;
  f32x4 acc[4][4];
#pragma unroll
  for (int x = 0; x < 4; ++x)
#pragma unroll
    for (int y = 0; y < 4; ++y) acc[x][y] = (f32x4)0.f;
  gemm_tile(Ap, AA, Bp, AA, AA / 64, smem, smem + 16384, acc);
  const int lane = threadIdx.x & 63, wid = threadIdx.x >> 6;
  const int r0 = i * 128 + (wid >> 1) * 64, c0 = j * 128 + (wid & 1) * 64;
#pragma unroll
  for (int mi = 0; mi < 4; ++mi)
#pragma unroll
    for (int r = 0; r < 4; ++r) {
      const int row = r0 + mi * 16 + ((lane >> 4) << 2) + r;
      float psum = 0.f;
#pragma unroll
      for (int ni = 0; ni < 4; ++ni) {
        const int col = c0 + ni * 16 + (lane & 15);
        float e = (col <= row) ? __expf(acc[mi][ni][r] * 0.03125f) : 0.f;
        psum += e;
        Op[(size_t)row * SS + col] = f2bf(e);
      }
      psum += __shfl_xor(psum, 1, 16);
      psum += __shfl_xor(psum, 2, 16);
      psum += __shfl_xor(psum, 4, 16);
      psum += __shfl_xor(psum, 8, 16);
      if ((lane & 15) == 0) atomicAdd(&rs[row], psum);
    }
}

// ---------- out = (P @ Vt^T) / rowsum (causal K-loop), fp32 out ----------
// Perfect XCD balance: XCD x handles i in {x, 15-x} -> per-XCD work = 17 units per (b,half-pair),
// 68 units total per XCD = exactly total/8.
__global__ __launch_bounds__(256) void k_pv(const u16* __restrict__ Sc, const u16* __restrict__ Vt,
                                            const float* __restrict__ rowsum, float* __restrict__ Out) {
  __shared__ __align__(16) char smem[32768];
  const int lin = blockIdx.x;          // 512; lin&7 = XCD
  const int x = lin & 7;
  const int j = lin >> 3;              // [0,64)
  const int b = j >> 4, half = (j >> 3) & 1, nt = j & 7;
  const int i = half ? (15 - x) : x;
  const u16* Ap = Sc + (size_t)b * SS * SS + (size_t)i * 128 * SS;
  const u16* Bp = Vt + (size_t)b * AA * SS + (size_t)nt * 128 * SS;
  const float* rs = rowsum + (size_t)b * SS;
  float* Op = Out + (size_t)b * SS * AA;
  f32x4 acc[4][4];
#pragma unroll
  for (int p = 0; p < 4; ++p)
#pragma unroll
    for (int q = 0; q < 4; ++q) acc[p][q] = (f32x4)0.f;
  gemm_tile(Ap, SS, Bp, SS, 2 * (i + 1), smem, smem + 16384, acc);
  const int lane = threadIdx.x & 63, wid = threadIdx.x >> 6;
  const int r0 = i * 128 + (wid >> 1) * 64, c0 = nt * 128 + (wid & 1) * 64;
#pragma unroll
  for (int mi = 0; mi < 4; ++mi)
#pragma unroll
    for (int r = 0; r < 4; ++r) {
      const int row = r0 + mi * 16 + ((lane >> 4) << 2) + r;
      const float inv = 1.f / rs[row];
#pragma unroll
      for (int ni = 0; ni < 4; ++ni) {
        const int col = c0 + ni * 16 + (lane & 15);
        Op[(size_t)row * AA + col] = acc[mi][ni][r] * inv;
      }
    }
}

extern "C" void kernel_launch(void* const* d_in, const int* in_sizes, int n_in,
                              void* d_out, int out_size, void* d_ws, size_t ws_size,
                              hipStream_t stream) {
  const float* X  = (const float*)d_in[0];
  const float* Wq = (const float*)d_in[1];
  const float* Wk = (const float*)d_in[2];
  const float* Wv = (const float*)d_in[3];
  float* Out = (float*)d_out;
  char* ws = (char*)d_ws;
  u16* Xb = (u16*)ws;                              // 16 MiB: [8192][1024]
  u16* Wt = (u16*)(ws + (16u << 20));              // 6 MiB: [3072][1024] (n-major, Q|K|V)
  u16* Qb = (u16*)(ws + (22u << 20));              // 16 MiB  } contiguous:
  u16* Kb = (u16*)(ws + (38u << 20));              // 16 MiB  }  Qb + w*8192*1024
  u16* Vb = (u16*)(ws + (54u << 20));              // 16 MiB  }
  u16* Vt = (u16*)(ws + (70u << 20));              // 16 MiB: per-batch [1024][2048]
  u16* Sc = (u16*)(ws + (86u << 20));              // 32 MiB: [4][2048][2048]
  float* rowsum = (float*)(ws + (118u << 20));     // 32 KiB: [4][2048]

  k_prep<<<dim3(8192 + 768), 256, 0, stream>>>(X, Wq, Wk, Wv, Xb, Wt, rowsum);
  k_proj3<<<dim3(768), 512, 0, stream>>>(Xb, Wt, Qb);
  k_vt<<<dim3(SS / 64, AA / 64, BB), 256, 0, stream>>>(Vb, Vt);
  k_scores<<<dim3(136 * BB), 256, 0, stream>>>(Qb, Kb, Sc, rowsum);
  k_pv<<<dim3(512), 256, 0, stream>>>(Sc, Vt, rowsum, Out);
}

// Round 6
// 167.399 us; speedup vs baseline: 1.0435x; 1.0261x over previous
//
#include <hip/hip_runtime.h>
#include <hip/hip_bf16.h>

#define DI __device__ __forceinline__

typedef __attribute__((ext_vector_type(8))) __bf16 bf16x8;
typedef __attribute__((ext_vector_type(4))) float f32x4;
typedef __attribute__((ext_vector_type(8))) short short8;
typedef __attribute__((ext_vector_type(4))) short short4v;
typedef unsigned short u16;

static constexpr int BB = 4, SS = 2048, EE = 1024, AA = 1024;

DI float bf2f(u16 u) { unsigned v = ((unsigned)u) << 16; float f; __builtin_memcpy(&f, &v, 4); return f; }
DI u16 f2bf(float f) { __hip_bfloat16 h = __float2bfloat16(f); u16 u; __builtin_memcpy(&u, &h, 2); return u; }

DI void gload16(const void* g, void* l) {
  __builtin_amdgcn_global_load_lds((const __attribute__((address_space(1))) void*)g,
                                   (__attribute__((address_space(3))) void*)l, 16, 0, 0);
}

// bijective XCD swizzle: nwg % 8 == 0.
DI int xcd_swz(int lin, int nwg) {
  int cpx = nwg >> 3;
  return (lin & 7) * cpx + (lin >> 3);
}

// LDS tile rows are 128B (64 bf16). Physical 16B chunk = logical ^ (row&7).
DI bf16x8 read_frag(const char* lds, int R, int c) {
  return *(const bf16x8*)(lds + R * 128 + ((c ^ (R & 7)) << 4));
}

// ================= proj: 256x256 4-phase pipelined GEMM, C[8192][3072] = Xb @ Wt^T =================
// 512 threads = 8 waves (2M x 4N), wave owns 128x64. BK=64, 16 K-tiles.
// Double-buffered LDS 128KB (A 32KB + B 32KB per buffer). Per K-tile: 4 phases of 16 MFMA;
// all 8 stage loads of tile t+1 issued in phases 0-1; one vmcnt(0) at tile end (loads issued
// >=2 phases earlier -> landed; drain is cheap). V-output (nt>=8) written TRANSPOSED to Vt.
__global__ __launch_bounds__(512, 2) void k_proj4(const u16* __restrict__ Xb, const u16* __restrict__ Wt,
                                                  u16* __restrict__ Qb, u16* __restrict__ Vt) {
  __shared__ __align__(16) char smem[131072];
  const int tid = threadIdx.x, lane = tid & 63, wid = tid >> 6;
  const int wr = wid >> 2, wc = wid & 3;        // 2M x 4N waves
  const int lane15 = lane & 15, lhi = lane >> 4;
  const int lin = blockIdx.x;                   // 384 wgs; lin&7 = XCD
  const int jj = lin >> 3;                      // [0,48) within XCD
  const int mt = (lin & 7) * 4 + (jj & 3);      // [0,32): 4 m-tiles per XCD
  const int nt = jj >> 2;                       // [0,12): m-fastest
  const u16* Ap = Xb + (size_t)mt * 256 * EE;
  const u16* Bp = Wt + (size_t)nt * 256 * EE;

  auto stageA = [&](int t, char* buf) {         // full 256x64 A tile: 4 loads/thread
#pragma unroll
    for (int i = 0; i < 4; ++i) {
      int blk = i * 8 + wid;                    // 1KB block 0..31
      int r = blk * 8 + (lane >> 3);            // row 0..255
      int c = (lane & 7) ^ (r & 7);
      gload16((const char*)(Ap + (size_t)t * 64 + (size_t)r * EE) + c * 16, buf + blk * 1024);
    }
  };
  auto stageB = [&](int t, char* buf) {
#pragma unroll
    for (int i = 0; i < 4; ++i) {
      int blk = i * 8 + wid;
      int r = blk * 8 + (lane >> 3);
      int c = (lane & 7) ^ (r & 7);
      gload16((const char*)(Bp + (size_t)t * 64 + (size_t)r * EE) + c * 16, buf + 32768 + blk * 1024);
    }
  };

  f32x4 acc[8][4];
#pragma unroll
  for (int i = 0; i < 8; ++i)
#pragma unroll
    for (int j = 0; j < 4; ++j) acc[i][j] = (f32x4)0.f;

  stageA(0, smem); stageB(0, smem);
  asm volatile("s_waitcnt vmcnt(0)" ::: "memory");
  __builtin_amdgcn_s_barrier();

#pragma unroll 1
  for (int t = 0; t < 16; ++t) {
    const char* As = smem + (t & 1) * 65536;
    const char* Bs = As + 32768;
    char* nxt = smem + ((t & 1) ^ 1) * 65536;
    const bool st = (t + 1 < 16);
    bf16x8 bfr[4][2];

#pragma unroll
    for (int q = 0; q < 4; ++q) {
      // ds-reads for this phase (from cur)
      if (q == 0) {
#pragma unroll
        for (int ni = 0; ni < 4; ++ni)
#pragma unroll
          for (int ks = 0; ks < 2; ++ks)
            bfr[ni][ks] = read_frag(Bs, wc * 64 + ni * 16 + lane15, ks * 4 + lhi);
      }
      bf16x8 af[2][2];
#pragma unroll
      for (int m2 = 0; m2 < 2; ++m2)
#pragma unroll
        for (int ks = 0; ks < 2; ++ks)
          af[m2][ks] = read_frag(As, wr * 128 + (q * 2 + m2) * 16 + lane15, ks * 4 + lhi);
      // stage next tile early (phases 0,1): latency covered by >=2 phases of MFMA
      if (q == 0 && st) stageA(t + 1, nxt);
      if (q == 1 && st) stageB(t + 1, nxt);
      __builtin_amdgcn_s_barrier();
      asm volatile("s_waitcnt lgkmcnt(0)" ::: "memory");
      __builtin_amdgcn_sched_barrier(0);
      __builtin_amdgcn_s_setprio(1);
#pragma unroll
      for (int m2 = 0; m2 < 2; ++m2)
#pragma unroll
        for (int ni = 0; ni < 4; ++ni)
#pragma unroll
          for (int ks = 0; ks < 2; ++ks)
            acc[q * 2 + m2][ni] =
                __builtin_amdgcn_mfma_f32_16x16x32_bf16(af[m2][ks], bfr[ni][ks], acc[q * 2 + m2][ni], 0, 0, 0);
      __builtin_amdgcn_s_setprio(0);
      __builtin_amdgcn_sched_barrier(0);
      if (q == 3) asm volatile("s_waitcnt vmcnt(0)" ::: "memory");  // next tile landed (issued 2+ phases ago)
      __builtin_amdgcn_s_barrier();
    }
  }

  // epilogue: C/D layout col=lane&15, row=(lane>>4)*4+reg
  if (nt < 8) {
    const int w = nt >> 2;
    u16* Op = Qb + (size_t)w * ((size_t)BB * SS * AA);
    const int r0 = mt * 256 + wr * 128;
    const int c0 = (nt & 3) * 256 + wc * 64;
#pragma unroll
    for (int mi = 0; mi < 8; ++mi)
#pragma unroll
      for (int ni = 0; ni < 4; ++ni)
#pragma unroll
        for (int r = 0; r < 4; ++r) {
          int row = r0 + mi * 16 + lhi * 4 + r;
          int col = c0 + ni * 16 + lane15;
          Op[(size_t)row * AA + col] = f2bf(acc[mi][ni][r]);
        }
  } else {
    // V: write transposed. Vt[b][a][s] = V[b][s][a]; 4 consecutive rows = 8B chunk.
    const int r0 = mt * 256 + wr * 128;
    const int c0 = (nt - 8) * 256 + wc * 64;
#pragma unroll
    for (int mi = 0; mi < 8; ++mi) {
      const int grow = r0 + mi * 16 + lhi * 4;     // global s-row, 4 consecutive
      const int b = grow >> 11, s = grow & 2047;
#pragma unroll
      for (int ni = 0; ni < 4; ++ni) {
        const int col = c0 + ni * 16 + lane15;     // a-dim
        short4v o;
#pragma unroll
        for (int r = 0; r < 4; ++r) o[r] = (short)f2bf(acc[mi][ni][r]);
        *(short4v*)(Vt + (size_t)b * AA * SS + (size_t)col * SS + s) = o;
      }
    }
  }
}

// ================= 128x128 GEMM core (scores / pv) =================
DI void stage_tile(const u16* g, int ld, char* lds, int wid, int lane) {
#pragma unroll
  for (int i = 0; i < 4; ++i) {
    int blk = i * 4 + wid;
    int r = blk * 8 + (lane >> 3);
    int c = (lane & 7) ^ (r & 7);
    gload16((const char*)(g + (size_t)r * ld) + c * 16, lds + blk * 1024);
  }
}

DI void gemm_tile(const u16* Ap, int lda, const u16* Bp, int ldb, int ksteps,
                  char* As, char* Bs, f32x4 acc[4][4]) {
  const int tid = threadIdx.x, lane = tid & 63, wid = tid >> 6;
  const int wr = wid >> 1, wc = wid & 1;
  for (int ks = 0; ks < ksteps; ++ks) {
    __syncthreads();
    stage_tile(Ap + (size_t)ks * 64, lda, As, wid, lane);
    stage_tile(Bp + (size_t)ks * 64, ldb, Bs, wid, lane);
    asm volatile("s_waitcnt vmcnt(0)" ::: "memory");
    __syncthreads();
#pragma unroll
    for (int ksub = 0; ksub < 2; ++ksub) {
      const int c = ksub * 4 + (lane >> 4);
      bf16x8 af[4], bfr[4];
#pragma unroll
      for (int mi = 0; mi < 4; ++mi) af[mi] = read_frag(As, wr * 64 + mi * 16 + (lane & 15), c);
#pragma unroll
      for (int ni = 0; ni < 4; ++ni) bfr[ni] = read_frag(Bs, wc * 64 + ni * 16 + (lane & 15), c);
#pragma unroll
      for (int mi = 0; mi < 4; ++mi)
#pragma unroll
        for (int ni = 0; ni < 4; ++ni)
          acc[mi][ni] = __builtin_amdgcn_mfma_f32_16x16x32_bf16(af[mi], bfr[ni], acc[mi][ni], 0, 0, 0);
    }
  }
}

// ---------- prep: cast X -> bf16, cast+transpose W -> Wt, zero rowsum ----------
__global__ __launch_bounds__(256) void k_prep(const float* __restrict__ X, const float* __restrict__ Wq,
                                              const float* __restrict__ Wk, const float* __restrict__ Wv,
                                              u16* __restrict__ Xb, u16* __restrict__ Wt,
                                              float* __restrict__ rowsum) {
  __shared__ float t[64][65];
  const int bid = blockIdx.x;
  if (bid < 8192) {
    if (bid < 32) rowsum[bid * 256 + threadIdx.x] = 0.f;
    size_t i = ((size_t)bid * 256 + threadIdx.x) * 4;
    f32x4 f = *(const f32x4*)(X + i);
    short4v o;
#pragma unroll
    for (int j = 0; j < 4; ++j) o[j] = (short)f2bf(f[j]);
    *(short4v*)(Xb + i) = o;
  } else {
    const int bx = bid - 8192;                 // [0,768)
    const int w = bx >> 8, rem = bx & 255;
    const int k0 = (rem & 15) * 64, n0 = (rem >> 4) * 64;
    const float* W = (w == 0) ? Wq : ((w == 1) ? Wk : Wv);
    u16* Wo = Wt + (size_t)w * EE * AA;
    const int tx = threadIdx.x & 63, ty = threadIdx.x >> 6;
#pragma unroll
    for (int r = 0; r < 16; ++r) {
      int k = r * 4 + ty;
      t[k][tx] = W[(size_t)(k0 + k) * AA + n0 + tx];
    }
    __syncthreads();
#pragma unroll
    for (int r = 0; r < 16; ++r) {
      int n = r * 4 + ty;
      Wo[(size_t)(n0 + n) * EE + k0 + tx] = f2bf(t[tx][n]);
    }
  }
}

// ---------- P = exp(Q @ K^T / 32) causal, + rowsum atomics ----------
__global__ __launch_bounds__(256) void k_scores(const u16* __restrict__ Q, const u16* __restrict__ K,
                                                u16* __restrict__ Sc, float* __restrict__ rowsum) {
  __shared__ __align__(16) char smem[32768];
  const int wg = xcd_swz(blockIdx.x, 544);
  const int b = wg / 136, t = wg % 136;
  int i = (int)((sqrtf(8.f * t + 1.f) - 1.f) * 0.5f);
  while ((i + 1) * (i + 2) / 2 <= t) ++i;
  while (i * (i + 1) / 2 > t) --i;
  const int j = t - i * (i + 1) / 2;
  const u16* Ap = Q + (size_t)b * SS * AA + (size_t)i * 128 * AA;
  const u16* Bp = K + (size_t)b * SS * AA + (size_t)j * 128 * AA;
  u16* Op = Sc + (size_t)b * SS * SS;
  float* rs = rowsum + (size_t)b * SS;
  f32x4 acc[4][4];
#pragma unroll
  for (int x = 0; x < 4; ++x)
#pragma unroll
    for (int y = 0; y < 4; ++y) acc[x][y] = (f32x4)0.f;
  gemm_tile(Ap, AA, Bp, AA, AA / 64, smem, smem + 16384, acc);
  const int lane = threadIdx.x & 63, wid = threadIdx.x >> 6;
  const int r0 = i * 128 + (wid >> 1) * 64, c0 = j * 128 + (wid & 1) * 64;
#pragma unroll
  for (int mi = 0; mi < 4; ++mi)
#pragma unroll
    for (int r = 0; r < 4; ++r) {
      const int row = r0 + mi * 16 + ((lane >> 4) << 2) + r;
      float psum = 0.f;
#pragma unroll
      for (int ni = 0; ni < 4; ++ni) {
        const int col = c0 + ni * 16 + (lane & 15);
        float e = (col <= row) ? __expf(acc[mi][ni][r] * 0.03125f) : 0.f;
        psum += e;
        Op[(size_t)row * SS + col] = f2bf(e);
      }
      psum += __shfl_xor(psum, 1, 16);
      psum += __shfl_xor(psum, 2, 16);
      psum += __shfl_xor(psum, 4, 16);
      psum += __shfl_xor(psum, 8, 16);
      if ((lane & 15) == 0) atomicAdd(&rs[row], psum);
    }
}

// ---------- out = (P @ Vt^T) / rowsum (causal K-loop), fp32 out ----------
// Perfect XCD balance: XCD x handles i in {x, 15-x}.
__global__ __launch_bounds__(256) void k_pv(const u16* __restrict__ Sc, const u16* __restrict__ Vt,
                                            const float* __restrict__ rowsum, float* __restrict__ Out) {
  __shared__ __align__(16) char smem[32768];
  const int lin = blockIdx.x;          // 512; lin&7 = XCD
  const int x = lin & 7;
  const int j = lin >> 3;              // [0,64)
  const int b = j >> 4, half = (j >> 3) & 1, nt = j & 7;
  const int i = half ? (15 - x) : x;
  const u16* Ap = Sc + (size_t)b * SS * SS + (size_t)i * 128 * SS;
  const u16* Bp = Vt + (size_t)b * AA * SS + (size_t)nt * 128 * SS;
  const float* rs = rowsum + (size_t)b * SS;
  float* Op = Out + (size_t)b * SS * AA;
  f32x4 acc[4][4];
#pragma unroll
  for (int p = 0; p < 4; ++p)
#pragma unroll
    for (int q = 0; q < 4; ++q) acc[p][q] = (f32x4)0.f;
  gemm_tile(Ap, SS, Bp, SS, 2 * (i + 1), smem, smem + 16384, acc);
  const int lane = threadIdx.x & 63, wid = threadIdx.x >> 6;
  const int r0 = i * 128 + (wid >> 1) * 64, c0 = nt * 128 + (wid & 1) * 64;
#pragma unroll
  for (int mi = 0; mi < 4; ++mi)
#pragma unroll
    for (int r = 0; r < 4; ++r) {
      const int row = r0 + mi * 16 + ((lane >> 4) << 2) + r;
      const float inv = 1.f / rs[row];
#pragma unroll
      for (int ni = 0; ni < 4; ++ni) {
        const int col = c0 + ni * 16 + (lane & 15);
        Op[(size_t)row * AA + col] = acc[mi][ni][r] * inv;
      }
    }
}

extern "C" void kernel_launch(void* const* d_in, const int* in_sizes, int n_in,
                              void* d_out, int out_size, void* d_ws, size_t ws_size,
                              hipStream_t stream) {
  const float* X  = (const float*)d_in[0];
  const float* Wq = (const float*)d_in[1];
  const float* Wk = (const float*)d_in[2];
  const float* Wv = (const float*)d_in[3];
  float* Out = (float*)d_out;
  char* ws = (char*)d_ws;
  u16* Xb = (u16*)ws;                              // 16 MiB: [8192][1024]
  u16* Wt = (u16*)(ws + (16u << 20));              // 6 MiB: [3072][1024] (n-major, Q|K|V)
  u16* Qb = (u16*)(ws + (22u << 20));              // 16 MiB  } Qb, Kb contiguous
  u16* Kb = (u16*)(ws + (38u << 20));              // 16 MiB  }
  u16* Vt = (u16*)(ws + (70u << 20));              // 16 MiB: per-batch [1024][2048]
  u16* Sc = (u16*)(ws + (86u << 20));              // 32 MiB: [4][2048][2048]
  float* rowsum = (float*)(ws + (118u << 20));     // 32 KiB: [4][2048]
  (void)Kb;

  k_prep<<<dim3(8192 + 768), 256, 0, stream>>>(X, Wq, Wk, Wv, Xb, Wt, rowsum);
  k_proj4<<<dim3(384), 512, 0, stream>>>(Xb, Wt, Qb, Vt);
  k_scores<<<dim3(136 * BB), 256, 0, stream>>>(Qb, Kb, Sc, rowsum);
  k_pv<<<dim3(512), 256, 0, stream>>>(Sc, Vt, rowsum, Out);
}

// Round 7
// 142.779 us; speedup vs baseline: 1.2235x; 1.1724x over previous
//
#include <hip/hip_runtime.h>
#include <hip/hip_bf16.h>

#define DI __device__ __forceinline__

typedef __attribute__((ext_vector_type(8))) __bf16 bf16x8;
typedef __attribute__((ext_vector_type(4))) float f32x4;
typedef __attribute__((ext_vector_type(8))) short short8;
typedef __attribute__((ext_vector_type(4))) short short4v;
typedef unsigned short u16;

static constexpr int BB = 4, SS = 2048, EE = 1024, AA = 1024;

DI float bf2f(u16 u) { unsigned v = ((unsigned)u) << 16; float f; __builtin_memcpy(&f, &v, 4); return f; }
DI u16 f2bf(float f) { __hip_bfloat16 h = __float2bfloat16(f); u16 u; __builtin_memcpy(&u, &h, 2); return u; }

DI void gload16(const void* g, void* l) {
  __builtin_amdgcn_global_load_lds((const __attribute__((address_space(1))) void*)g,
                                   (__attribute__((address_space(3))) void*)l, 16, 0, 0);
}

// bijective XCD swizzle: nwg % 8 == 0.
DI int xcd_swz(int lin, int nwg) {
  int cpx = nwg >> 3;
  return (lin & 7) * cpx + (lin >> 3);
}

// LDS tile rows are 128B (64 bf16). Physical 16B chunk = logical ^ (row&7).
DI bf16x8 read_frag(const char* lds, int R, int c) {
  return *(const bf16x8*)(lds + R * 128 + ((c ^ (R & 7)) << 4));
}

// ================= proj: 256x192 4-phase pipelined GEMM, C[8192][3072] = Xb @ Wt^T =================
// 512 wgs = exactly 2 rounds of 256 CUs. 512 threads = 8 waves (2M x 4N), wave owns 128x48.
// BK=64, 16 K-tiles. Double-buffered LDS 112KB (A 32KB + B 24KB per buffer).
// Per K-tile: 4 phases of 12 MFMA; stage loads of t+1 issued in phases 0-1; vmcnt(0) at tile end.
__global__ __launch_bounds__(512, 2) void k_proj5(const u16* __restrict__ Xb, const u16* __restrict__ Wt,
                                                  u16* __restrict__ Qb, u16* __restrict__ Vt) {
  __shared__ __align__(16) char smem[114688];   // 2 x 56KB
  const int tid = threadIdx.x, lane = tid & 63, wid = tid >> 6;
  const int wr = wid >> 2, wc = wid & 3;        // 2M x 4N waves
  const int lane15 = lane & 15, lhi = lane >> 4;
  const int lin = blockIdx.x;                   // 512 wgs; lin&7 = XCD
  const int jj = lin >> 3;                      // [0,64) within XCD
  const int mt = (lin & 7) * 4 + (jj & 3);      // [0,32): 4 m-tiles per XCD
  const int nt = jj >> 2;                       // [0,16): m-fastest
  const u16* Ap = Xb + (size_t)mt * 256 * EE;
  const u16* Bp = Wt + (size_t)nt * 192 * EE;

  auto stageA = [&](int t, char* buf) {         // 256x64 A tile: 32 blocks, 4 insts/wave
#pragma unroll
    for (int i = 0; i < 4; ++i) {
      int blk = i * 8 + wid;
      int r = blk * 8 + (lane >> 3);            // row 0..255
      int c = (lane & 7) ^ (r & 7);
      gload16((const char*)(Ap + (size_t)t * 64 + (size_t)r * EE) + c * 16, buf + blk * 1024);
    }
  };
  auto stageB = [&](int t, char* buf) {         // 192x64 B tile: 24 blocks, 3 insts/wave
#pragma unroll
    for (int i = 0; i < 3; ++i) {
      int blk = i * 8 + wid;
      int r = blk * 8 + (lane >> 3);            // row 0..191
      int c = (lane & 7) ^ (r & 7);
      gload16((const char*)(Bp + (size_t)t * 64 + (size_t)r * EE) + c * 16, buf + 32768 + blk * 1024);
    }
  };

  f32x4 acc[8][3];
#pragma unroll
  for (int i = 0; i < 8; ++i)
#pragma unroll
    for (int j = 0; j < 3; ++j) acc[i][j] = (f32x4)0.f;

  stageA(0, smem); stageB(0, smem);
  asm volatile("s_waitcnt vmcnt(0)" ::: "memory");
  __builtin_amdgcn_s_barrier();

#pragma unroll 1
  for (int t = 0; t < 16; ++t) {
    const char* As = smem + (t & 1) * 57344;
    const char* Bs = As + 32768;
    char* nxt = smem + ((t & 1) ^ 1) * 57344;
    const bool st = (t + 1 < 16);
    bf16x8 bfr[3][2];

#pragma unroll
    for (int q = 0; q < 4; ++q) {
      if (q == 0) {
#pragma unroll
        for (int ni = 0; ni < 3; ++ni)
#pragma unroll
          for (int ks = 0; ks < 2; ++ks)
            bfr[ni][ks] = read_frag(Bs, wc * 48 + ni * 16 + lane15, ks * 4 + lhi);
      }
      bf16x8 af[2][2];
#pragma unroll
      for (int m2 = 0; m2 < 2; ++m2)
#pragma unroll
        for (int ks = 0; ks < 2; ++ks)
          af[m2][ks] = read_frag(As, wr * 128 + (q * 2 + m2) * 16 + lane15, ks * 4 + lhi);
      if (q == 0 && st) stageA(t + 1, nxt);
      if (q == 1 && st) stageB(t + 1, nxt);
      __builtin_amdgcn_s_barrier();
      asm volatile("s_waitcnt lgkmcnt(0)" ::: "memory");
      __builtin_amdgcn_sched_barrier(0);
      __builtin_amdgcn_s_setprio(1);
#pragma unroll
      for (int m2 = 0; m2 < 2; ++m2)
#pragma unroll
        for (int ni = 0; ni < 3; ++ni)
#pragma unroll
          for (int ks = 0; ks < 2; ++ks)
            acc[q * 2 + m2][ni] =
                __builtin_amdgcn_mfma_f32_16x16x32_bf16(af[m2][ks], bfr[ni][ks], acc[q * 2 + m2][ni], 0, 0, 0);
      __builtin_amdgcn_s_setprio(0);
      __builtin_amdgcn_sched_barrier(0);
      if (q == 3) asm volatile("s_waitcnt vmcnt(0)" ::: "memory");
      __builtin_amdgcn_s_barrier();
    }
  }

  // epilogue: C/D layout col=lane&15, row=(lane>>4)*4+reg. Cols [0,2048)=Q|K row-major
  // (Qb,Kb contiguous, 8192*1024 apart); cols [2048,3072) = V written TRANSPOSED to Vt.
  const int r0 = mt * 256 + wr * 128;
  const int c0 = nt * 192 + wc * 48;
#pragma unroll
  for (int mi = 0; mi < 8; ++mi) {
    const int grow = r0 + mi * 16 + lhi * 4;        // 4 consecutive s-rows (16-aligned chunk)
    const int b = grow >> 11, s = grow & 2047;
#pragma unroll
    for (int ni = 0; ni < 3; ++ni) {
      const int col = c0 + ni * 16 + lane15;        // 16-aligned chunk: col>>10 uniform per ni
      if (col < 2048) {
        u16* base = Qb + (size_t)(col >> 10) * ((size_t)BB * SS * AA);
#pragma unroll
        for (int r = 0; r < 4; ++r)
          base[(size_t)(grow + r) * AA + (col & 1023)] = f2bf(acc[mi][ni][r]);
      } else {
        const int a = col - 2048;
        short4v o;
#pragma unroll
        for (int r = 0; r < 4; ++r) o[r] = (short)f2bf(acc[mi][ni][r]);
        *(short4v*)(Vt + (size_t)b * AA * SS + (size_t)a * SS + s) = o;
      }
    }
  }
}

// ================= 128x128 GEMM core (scores / pv): T3-min double-buffered =================
DI void stage_tile(const u16* g, int ld, char* lds, int wid, int lane) {
#pragma unroll
  for (int i = 0; i < 4; ++i) {
    int blk = i * 4 + wid;
    int r = blk * 8 + (lane >> 3);
    int c = (lane & 7) ^ (r & 7);
    gload16((const char*)(g + (size_t)r * ld) + c * 16, lds + blk * 1024);
  }
}

// smem: 2 x 32KB buffers (As 16KB + Bs 16KB each). STAGE(t+1) issued before ds_read+MFMA of t;
// one vmcnt(0)+barrier per K-step (T3-minimum recipe).
DI void gemm_tile(const u16* Ap, int lda, const u16* Bp, int ldb, int ksteps,
                  char* smem, f32x4 acc[4][4]) {
  const int tid = threadIdx.x, lane = tid & 63, wid = tid >> 6;
  const int wr = wid >> 1, wc = wid & 1;
  stage_tile(Ap, lda, smem, wid, lane);
  stage_tile(Bp, ldb, smem + 16384, wid, lane);
  asm volatile("s_waitcnt vmcnt(0)" ::: "memory");
  __syncthreads();
#pragma unroll 1
  for (int ks = 0; ks < ksteps; ++ks) {
    const char* As = smem + (ks & 1) * 32768;
    const char* Bs = As + 16384;
    char* nxt = smem + ((ks & 1) ^ 1) * 32768;
    if (ks + 1 < ksteps) {
      stage_tile(Ap + (size_t)(ks + 1) * 64, lda, nxt, wid, lane);
      stage_tile(Bp + (size_t)(ks + 1) * 64, ldb, nxt + 16384, wid, lane);
    }
#pragma unroll
    for (int ksub = 0; ksub < 2; ++ksub) {
      const int c = ksub * 4 + (lane >> 4);
      bf16x8 af[4], bfr[4];
#pragma unroll
      for (int mi = 0; mi < 4; ++mi) af[mi] = read_frag(As, wr * 64 + mi * 16 + (lane & 15), c);
#pragma unroll
      for (int ni = 0; ni < 4; ++ni) bfr[ni] = read_frag(Bs, wc * 64 + ni * 16 + (lane & 15), c);
#pragma unroll
      for (int mi = 0; mi < 4; ++mi)
#pragma unroll
        for (int ni = 0; ni < 4; ++ni)
          acc[mi][ni] = __builtin_amdgcn_mfma_f32_16x16x32_bf16(af[mi], bfr[ni], acc[mi][ni], 0, 0, 0);
    }
    if (ks + 1 < ksteps) asm volatile("s_waitcnt vmcnt(0)" ::: "memory");
    __syncthreads();
  }
}

// ---------- prep: cast X -> bf16, cast+transpose W -> Wt, zero rowsum ----------
__global__ __launch_bounds__(256) void k_prep(const float* __restrict__ X, const float* __restrict__ Wq,
                                              const float* __restrict__ Wk, const float* __restrict__ Wv,
                                              u16* __restrict__ Xb, u16* __restrict__ Wt,
                                              float* __restrict__ rowsum) {
  __shared__ float t[64][65];
  const int bid = blockIdx.x;
  if (bid < 8192) {
    if (bid < 32) rowsum[bid * 256 + threadIdx.x] = 0.f;
    size_t i = ((size_t)bid * 256 + threadIdx.x) * 4;
    f32x4 f = *(const f32x4*)(X + i);
    short4v o;
#pragma unroll
    for (int j = 0; j < 4; ++j) o[j] = (short)f2bf(f[j]);
    *(short4v*)(Xb + i) = o;
  } else {
    const int bx = bid - 8192;                 // [0,768)
    const int w = bx >> 8, rem = bx & 255;
    const int k0 = (rem & 15) * 64, n0 = (rem >> 4) * 64;
    const float* W = (w == 0) ? Wq : ((w == 1) ? Wk : Wv);
    u16* Wo = Wt + (size_t)w * EE * AA;
    const int tx = threadIdx.x & 63, ty = threadIdx.x >> 6;
#pragma unroll
    for (int r = 0; r < 16; ++r) {
      int k = r * 4 + ty;
      t[k][tx] = W[(size_t)(k0 + k) * AA + n0 + tx];
    }
    __syncthreads();
#pragma unroll
    for (int r = 0; r < 16; ++r) {
      int n = r * 4 + ty;
      Wo[(size_t)(n0 + n) * EE + k0 + tx] = f2bf(t[tx][n]);
    }
  }
}

// ---------- P = exp(Q @ K^T / 32) causal, + rowsum atomics ----------
__global__ __launch_bounds__(256) void k_scores(const u16* __restrict__ Q, const u16* __restrict__ K,
                                                u16* __restrict__ Sc, float* __restrict__ rowsum) {
  __shared__ __align__(16) char smem[65536];
  const int wg = xcd_swz(blockIdx.x, 544);
  const int b = wg / 136, t = wg % 136;
  int i = (int)((sqrtf(8.f * t + 1.f) - 1.f) * 0.5f);
  while ((i + 1) * (i + 2) / 2 <= t) ++i;
  while (i * (i + 1) / 2 > t) --i;
  const int j = t - i * (i + 1) / 2;
  const u16* Ap = Q + (size_t)b * SS * AA + (size_t)i * 128 * AA;
  const u16* Bp = K + (size_t)b * SS * AA + (size_t)j * 128 * AA;
  u16* Op = Sc + (size_t)b * SS * SS;
  float* rs = rowsum + (size_t)b * SS;
  f32x4 acc[4][4];
#pragma unroll
  for (int x = 0; x < 4; ++x)
#pragma unroll
    for (int y = 0; y < 4; ++y) acc[x][y] = (f32x4)0.f;
  gemm_tile(Ap, AA, Bp, AA, AA / 64, smem, acc);
  const int lane = threadIdx.x & 63, wid = threadIdx.x >> 6;
  const int r0 = i * 128 + (wid >> 1) * 64, c0 = j * 128 + (wid & 1) * 64;
#pragma unroll
  for (int mi = 0; mi < 4; ++mi)
#pragma unroll
    for (int r = 0; r < 4; ++r) {
      const int row = r0 + mi * 16 + ((lane >> 4) << 2) + r;
      float psum = 0.f;
#pragma unroll
      for (int ni = 0; ni < 4; ++ni) {
        const int col = c0 + ni * 16 + (lane & 15);
        float e = (col <= row) ? __expf(acc[mi][ni][r] * 0.03125f) : 0.f;
        psum += e;
        Op[(size_t)row * SS + col] = f2bf(e);
      }
      psum += __shfl_xor(psum, 1, 16);
      psum += __shfl_xor(psum, 2, 16);
      psum += __shfl_xor(psum, 4, 16);
      psum += __shfl_xor(psum, 8, 16);
      if ((lane & 15) == 0) atomicAdd(&rs[row], psum);
    }
}

// ---------- out = (P @ Vt^T) / rowsum (causal K-loop), fp32 out ----------
// Perfect XCD balance: XCD x handles i in {x, 15-x}.
__global__ __launch_bounds__(256) void k_pv(const u16* __restrict__ Sc, const u16* __restrict__ Vt,
                                            const float* __restrict__ rowsum, float* __restrict__ Out) {
  __shared__ __align__(16) char smem[65536];
  const int lin = blockIdx.x;          // 512; lin&7 = XCD
  const int x = lin & 7;
  const int j = lin >> 3;              // [0,64)
  const int b = j >> 4, half = (j >> 3) & 1, nt = j & 7;
  const int i = half ? (15 - x) : x;
  const u16* Ap = Sc + (size_t)b * SS * SS + (size_t)i * 128 * SS;
  const u16* Bp = Vt + (size_t)b * AA * SS + (size_t)nt * 128 * SS;
  const float* rs = rowsum + (size_t)b * SS;
  float* Op = Out + (size_t)b * SS * AA;
  f32x4 acc[4][4];
#pragma unroll
  for (int p = 0; p < 4; ++p)
#pragma unroll
    for (int q = 0; q < 4; ++q) acc[p][q] = (f32x4)0.f;
  gemm_tile(Ap, SS, Bp, SS, 2 * (i + 1), smem, acc);
  const int lane = threadIdx.x & 63, wid = threadIdx.x >> 6;
  const int r0 = i * 128 + (wid >> 1) * 64, c0 = nt * 128 + (wid & 1) * 64;
#pragma unroll
  for (int mi = 0; mi < 4; ++mi)
#pragma unroll
    for (int r = 0; r < 4; ++r) {
      const int row = r0 + mi * 16 + ((lane >> 4) << 2) + r;
      const float inv = 1.f / rs[row];
#pragma unroll
      for (int ni = 0; ni < 4; ++ni) {
        const int col = c0 + ni * 16 + (lane & 15);
        Op[(size_t)row * AA + col] = acc[mi][ni][r] * inv;
      }
    }
}

extern "C" void kernel_launch(void* const* d_in, const int* in_sizes, int n_in,
                              void* d_out, int out_size, void* d_ws, size_t ws_size,
                              hipStream_t stream) {
  const float* X  = (const float*)d_in[0];
  const float* Wq = (const float*)d_in[1];
  const float* Wk = (const float*)d_in[2];
  const float* Wv = (const float*)d_in[3];
  float* Out = (float*)d_out;
  char* ws = (char*)d_ws;
  u16* Xb = (u16*)ws;                              // 16 MiB: [8192][1024]
  u16* Wt = (u16*)(ws + (16u << 20));              // 6 MiB: [3072][1024] (n-major, Q|K|V)
  u16* Qb = (u16*)(ws + (22u << 20));              // 16 MiB  } Qb, Kb contiguous (16MiB apart)
  u16* Kb = (u16*)(ws + (38u << 20));              // 16 MiB  }
  u16* Vt = (u16*)(ws + (70u << 20));              // 16 MiB: per-batch [1024][2048]
  u16* Sc = (u16*)(ws + (86u << 20));              // 32 MiB: [4][2048][2048]
  float* rowsum = (float*)(ws + (118u << 20));     // 32 KiB: [4][2048]

  k_prep<<<dim3(8192 + 768), 256, 0, stream>>>(X, Wq, Wk, Wv, Xb, Wt, rowsum);
  k_proj5<<<dim3(512), 512, 0, stream>>>(Xb, Wt, Qb, Vt);
  k_scores<<<dim3(136 * BB), 256, 0, stream>>>(Qb, Kb, Sc, rowsum);
  k_pv<<<dim3(512), 256, 0, stream>>>(Sc, Vt, rowsum, Out);
}